// Round 2
// baseline (267.311 us; speedup 1.0000x reference)
//
#include <hip/hip_runtime.h>
#include <hip/hip_bf16.h>

// DCRNN single-step, algebraically reduced:
//   xm = x * mask
//   Z  = sigmoid(xm @ WzE + bz),  WzE = w_z[0,0][:256] + w_z[1,0][:256]
//   Ht = tanh   (xm @ WhE + bh)
//   h  = elu((1 - Z) * Ht)          // H=0 -> Z*H term drops; R (w_r,b_r) is dead
//   out = h @ w_lin.T + b_lin       // OUTPUT IS FLOAT32 (reference returns f32)
// edge_index / edge_weight unused (K=1 diffusion keeps only the identity term).

constexpr int N_ROWS = 50000;
constexpr int CIN    = 256;
constexpr int CHID   = 256;
constexpr int COUT   = 64;
constexpr int ROWS_PER_BLK = 32;

__global__ __launch_bounds__(256) void prep_kernel(
    const float* __restrict__ wz, const float* __restrict__ wh,
    const float* __restrict__ wlin,
    float* __restrict__ WzE, float* __restrict__ WhE, float* __restrict__ WlT)
{
    int i = blockIdx.x * 256 + threadIdx.x;
    if (i < CIN * CHID) {
        // w shape (2,1,512,256); tap0 entry [k*256+j], tap1 at [512*256 + k*256+j]
        WzE[i] = wz[i] + wz[512 * CHID + i];
        WhE[i] = wh[i] + wh[512 * CHID + i];
    }
    if (i < CHID * COUT) {
        int k = i >> 6, o = i & 63;
        WlT[i] = wlin[o * CHID + k];   // WlT[k][o] = w_lin[o][k]
    }
}

template <bool USE_WS>
__global__ __launch_bounds__(256) void fused_kernel(
    const float* __restrict__ x, const float* __restrict__ mask,
    const float* __restrict__ WzE, const float* __restrict__ WhE,   // USE_WS: prepped; else raw w_z/w_h
    const float* __restrict__ bz, const float* __restrict__ bh,
    const float* __restrict__ WlT,                                   // USE_WS: transposed; else raw w_lin
    const float* __restrict__ blin,
    float* __restrict__ out)
{
    __shared__ float xm[ROWS_PER_BLK][CIN];    // 32 KB; reused for h after gates
    const int tid  = threadIdx.x;
    const int row0 = blockIdx.x * ROWS_PER_BLK;

    // ---- Stage xm = x * mask (float4, coalesced) ----
    #pragma unroll
    for (int it = 0; it < 8; ++it) {
        int idx = it * 256 + tid;       // float4 slot in the 32x256 tile
        int r   = idx >> 6;             // 64 float4 per row
        int c4  = idx & 63;
        int row = row0 + r;
        float4 v = make_float4(0.f, 0.f, 0.f, 0.f);
        if (row < N_ROWS) {
            float4 a = reinterpret_cast<const float4*>(x    + (size_t)row * CIN)[c4];
            float4 m = reinterpret_cast<const float4*>(mask + (size_t)row * CIN)[c4];
            v = make_float4(a.x * m.x, a.y * m.y, a.z * m.z, a.w * m.w);
        }
        reinterpret_cast<float4*>(&xm[r][0])[c4] = v;
    }
    __syncthreads();

    // ---- Gate GEMMs: thread owns 4 cols (j0..j0+3) x 8 rows (r0..r0+7) ----
    const int jc = tid & 63;
    const int rg = tid >> 6;
    const int j0 = jc * 4;
    const int r0 = rg * 8;

    float accz[4][8], acch[4][8];
    #pragma unroll
    for (int c = 0; c < 4; ++c)
        #pragma unroll
        for (int r = 0; r < 8; ++r) { accz[c][r] = 0.f; acch[c][r] = 0.f; }

    for (int k = 0; k < CIN; k += 4) {
        float4 wz4[4], wh4[4];
        #pragma unroll
        for (int kk = 0; kk < 4; ++kk) {
            if constexpr (USE_WS) {
                wz4[kk] = *reinterpret_cast<const float4*>(&WzE[(k + kk) * CHID + j0]);
                wh4[kk] = *reinterpret_cast<const float4*>(&WhE[(k + kk) * CHID + j0]);
            } else {
                float4 a0 = *reinterpret_cast<const float4*>(&WzE[(k + kk) * CHID + j0]);
                float4 a1 = *reinterpret_cast<const float4*>(&WzE[512 * CHID + (k + kk) * CHID + j0]);
                wz4[kk] = make_float4(a0.x + a1.x, a0.y + a1.y, a0.z + a1.z, a0.w + a1.w);
                float4 b0 = *reinterpret_cast<const float4*>(&WhE[(k + kk) * CHID + j0]);
                float4 b1 = *reinterpret_cast<const float4*>(&WhE[512 * CHID + (k + kk) * CHID + j0]);
                wh4[kk] = make_float4(b0.x + b1.x, b0.y + b1.y, b0.z + b1.z, b0.w + b1.w);
            }
        }
        #pragma unroll
        for (int r = 0; r < 8; ++r) {
            float4 xv = *reinterpret_cast<const float4*>(&xm[r0 + r][k]);  // broadcast read
            float xk[4] = {xv.x, xv.y, xv.z, xv.w};
            #pragma unroll
            for (int kk = 0; kk < 4; ++kk) {
                float wzc[4] = {wz4[kk].x, wz4[kk].y, wz4[kk].z, wz4[kk].w};
                float whc[4] = {wh4[kk].x, wh4[kk].y, wh4[kk].z, wh4[kk].w};
                #pragma unroll
                for (int c = 0; c < 4; ++c) {
                    accz[c][r] = fmaf(xk[kk], wzc[c], accz[c][r]);
                    acch[c][r] = fmaf(xk[kk], whc[c], acch[c][r]);
                }
            }
        }
    }

    float bzj[4], bhj[4];
    #pragma unroll
    for (int c = 0; c < 4; ++c) { bzj[c] = bz[j0 + c]; bhj[c] = bh[j0 + c]; }

    __syncthreads();   // everyone done reading xm before we overwrite with h

    // ---- Nonlinearities + GRU blend, h back into LDS ----
    #pragma unroll
    for (int r = 0; r < 8; ++r) {
        float hc[4];
        #pragma unroll
        for (int c = 0; c < 4; ++c) {
            float z  = 1.f / (1.f + expf(-(accz[c][r] + bzj[c])));
            float ht = tanhf(acch[c][r] + bhj[c]);
            float H  = (1.f - z) * ht;
            hc[c] = (H > 0.f) ? H : expm1f(H);   // elu(alpha=1)
        }
        *reinterpret_cast<float4*>(&xm[r0 + r][j0]) = make_float4(hc[0], hc[1], hc[2], hc[3]);
    }
    __syncthreads();

    // ---- Output GEMM: out[row][o] = h[row] . w_lin[o] + b_lin[o] ----
    const int o = tid & 63;     // lane -> output col (coalesced f32 stores)
    float acc[8];
    #pragma unroll
    for (int r = 0; r < 8; ++r) acc[r] = 0.f;

    for (int k = 0; k < CHID; k += 4) {
        float w0, w1, w2, w3;
        if constexpr (USE_WS) {
            w0 = WlT[(k + 0) * COUT + o];
            w1 = WlT[(k + 1) * COUT + o];
            w2 = WlT[(k + 2) * COUT + o];
            w3 = WlT[(k + 3) * COUT + o];
        } else {
            float4 wv = *reinterpret_cast<const float4*>(&WlT[o * CHID + k]);  // raw w_lin[o][k..k+3]
            w0 = wv.x; w1 = wv.y; w2 = wv.z; w3 = wv.w;
        }
        #pragma unroll
        for (int r = 0; r < 8; ++r) {
            float4 hv = *reinterpret_cast<const float4*>(&xm[r0 + r][k]);  // broadcast
            acc[r] = fmaf(hv.x, w0, acc[r]);
            acc[r] = fmaf(hv.y, w1, acc[r]);
            acc[r] = fmaf(hv.z, w2, acc[r]);
            acc[r] = fmaf(hv.w, w3, acc[r]);
        }
    }
    float bo = blin[o];
    #pragma unroll
    for (int r = 0; r < 8; ++r) {
        int row = row0 + r0 + r;
        if (row < N_ROWS)
            out[(size_t)row * COUT + o] = acc[r] + bo;   // FLOAT32 store
    }
}

extern "C" void kernel_launch(void* const* d_in, const int* in_sizes, int n_in,
                              void* d_out, int out_size, void* d_ws, size_t ws_size,
                              hipStream_t stream)
{
    const float* x    = (const float*)d_in[0];
    // d_in[1] edge_index, d_in[2] edge_weight: unused (K=1 identity term only)
    const float* mask = (const float*)d_in[3];
    const float* wz   = (const float*)d_in[4];
    const float* bz   = (const float*)d_in[5];
    // d_in[6] w_r, d_in[7] b_r: dead code (H=0 -> reset gate never used)
    const float* wh   = (const float*)d_in[8];
    const float* bh   = (const float*)d_in[9];
    const float* wlin = (const float*)d_in[10];
    const float* blin = (const float*)d_in[11];

    float* outf = (float*)d_out;
    const int grid = (N_ROWS + ROWS_PER_BLK - 1) / ROWS_PER_BLK;

    const size_t ws_need = (size_t)(2 * CIN * CHID + CHID * COUT) * sizeof(float); // 576 KB
    if (ws_size >= ws_need) {
        float* WzE = (float*)d_ws;
        float* WhE = WzE + CIN * CHID;
        float* WlT = WhE + CIN * CHID;
        prep_kernel<<<(CIN * CHID + 255) / 256, 256, 0, stream>>>(wz, wh, wlin, WzE, WhE, WlT);
        fused_kernel<true><<<grid, 256, 0, stream>>>(x, mask, WzE, WhE, bz, bh, WlT, blin, outf);
    } else {
        // workspace-free fallback: tap-sum and w_lin transpose done inline
        fused_kernel<false><<<grid, 256, 0, stream>>>(x, mask, wz, wh, bz, bh, wlin, blin, outf);
    }
}

// Round 4
// 120.900 us; speedup vs baseline: 2.2110x; 2.2110x over previous
//
#include <hip/hip_runtime.h>
#include <hip/hip_bf16.h>

// DCRNN single-step, algebraically reduced (math verified passing: rounds 2 & 3 first-call):
//   xm = x * mask
//   Z  = sigmoid(xm @ WzE + bz),  WzE = w_z[0,0][:256] + w_z[1,0][:256]
//   Ht = tanh   (xm @ WhE + bh)
//   h  = elu((1 - Z) * Ht)         // H=0 -> Z*H drops; R/w_r/b_r dead; edges dead
//   out = h @ w_lin.T + b_lin      // f32 output
//
// Split-bf16 MFMA (v = hi + lo; hi*hi + lo*hi + hi*lo, f32 acc) — round-3 math kept.
// Round-4 hardening: h round-trip through LDS is f32 word-granular (no sub-word
// LDS stores), hi/lo split for the out-GEMM done in-register; no launch_bounds cap.

typedef __attribute__((ext_vector_type(8))) short bf16x8;   // 8 bf16 = 4 VGPR
typedef __attribute__((ext_vector_type(4))) float f32x4;

constexpr int N_ROWS = 50000;
constexpr int CIN  = 256;
constexpr int COUT = 64;
constexpr int BM   = 64;

__device__ inline unsigned short f2bf(float f) {          // RNE f32 -> bf16 bits
    union { float f; unsigned u; } v; v.f = f;
    unsigned r = v.u + 0x7fffu + ((v.u >> 16) & 1u);
    return (unsigned short)(r >> 16);
}
__device__ inline float bf2f(unsigned short b) {
    union { unsigned u; float f; } v; v.u = ((unsigned)b) << 16;
    return v.f;
}
__device__ inline f32x4 mfma16(bf16x8 a, bf16x8 b, f32x4 c) {
    return __builtin_amdgcn_mfma_f32_16x16x32_bf16(a, b, c, 0, 0, 0);
}

// ---------------- weight prep: B-fragment-ordered hi/lo bf16 (proven round 3) ----------------
// Fragment f holds, for lane l, 8 bf16: B[k = kb*32 + (l>>4)*8 + j][n = nf*16 + (l&15)]
// gate frags f = ((g*2+p)*16 + nf)*8 + kb   g:0=Z,1=H  p:0=hi,1=lo  nf<16 kb<8  -> [0,512)
// out  frags f = 512 + (p*4 + nf)*8 + kb    nf<4                               -> [512,576)
__global__ __launch_bounds__(256) void prep_frags(
    const float* __restrict__ wz, const float* __restrict__ wh,
    const float* __restrict__ wlin, unsigned short* __restrict__ ws)
{
    int t = blockIdx.x * 256 + threadIdx.x;
    int frag = t >> 6, lane = t & 63;
    if (frag >= 576) return;
    int g16 = lane & 15, kg = lane >> 4;
    unsigned short vals[8];
    if (frag < 512) {
        int kb = frag & 7, nf = (frag >> 3) & 15, p = (frag >> 7) & 1, g = frag >> 8;
        const float* wsrc = g ? wh : wz;
        int n = nf * 16 + g16;
        #pragma unroll
        for (int j = 0; j < 8; ++j) {
            int k = kb * 32 + kg * 8 + j;
            float v = wsrc[k * 256 + n] + wsrc[131072 + k * 256 + n];  // tap0 + tap1
            unsigned short hi = f2bf(v);
            vals[j] = (p == 0) ? hi : f2bf(v - bf2f(hi));
        }
    } else {
        int f = frag - 512;
        int kb = f & 7, nf = (f >> 3) & 3, p = f >> 5;
        int n = nf * 16 + g16;                       // output column o
        #pragma unroll
        for (int j = 0; j < 8; ++j) {
            int k = kb * 32 + kg * 8 + j;
            float v = wlin[n * 256 + k];             // B[k][o] = w_lin[o][k]
            unsigned short hi = f2bf(v);
            vals[j] = (p == 0) ? hi : f2bf(v - bf2f(hi));
        }
    }
    unsigned short* dst = ws + (size_t)frag * 512 + lane * 8;
    #pragma unroll
    for (int j = 0; j < 8; ++j) dst[j] = vals[j];
}

__device__ inline bf16x8 ldfrag(const unsigned short* wf, int frag, int lane) {
    return *reinterpret_cast<const bf16x8*>(wf + (size_t)frag * 512 + lane * 8);
}

// ---------------- fused MFMA kernel ----------------
__global__ __launch_bounds__(256) void dcrnn_mfma(
    const float* __restrict__ x, const float* __restrict__ mask,
    const unsigned short* __restrict__ wf,
    const float* __restrict__ bz, const float* __restrict__ bh,
    const float* __restrict__ blin, float* __restrict__ out)
{
    __shared__ char smem[65536];               // phase A/B: Ahi|Alo bf16; phase C: h as f32
    char* AhiB = smem;                         // 32 KB, XOR-swizzled bf16 x_hi
    char* AloB = smem + 32768;                 // 32 KB, XOR-swizzled bf16 x_lo
    const int tid = threadIdx.x, lane = tid & 63, wv = tid >> 6;
    const int l16 = lane & 15, lk = lane >> 4;
    const int row0 = blockIdx.x * BM;

    // ---- stage xm = x*mask -> hi/lo bf16 in LDS (coalesced f32x4, swizzled 8B writes) ----
    #pragma unroll
    for (int it = 0; it < 16; ++it) {
        int f = it * 256 + tid;                // float4 slot in 64x256 tile
        int r = f >> 6, c4 = f & 63;
        int row = row0 + r;
        float4 xv = make_float4(0.f, 0.f, 0.f, 0.f), mv = xv;
        if (row < N_ROWS) {
            xv = reinterpret_cast<const float4*>(x    + (size_t)row * CIN)[c4];
            mv = reinterpret_cast<const float4*>(mask + (size_t)row * CIN)[c4];
        }
        float v0 = xv.x * mv.x, v1 = xv.y * mv.y, v2 = xv.z * mv.z, v3 = xv.w * mv.w;
        unsigned short h0 = f2bf(v0), h1 = f2bf(v1), h2 = f2bf(v2), h3 = f2bf(v3);
        unsigned short l0 = f2bf(v0 - bf2f(h0)), l1 = f2bf(v1 - bf2f(h1));
        unsigned short l2 = f2bf(v2 - bf2f(h2)), l3 = f2bf(v3 - bf2f(h3));
        int byte = ((r * CIN + c4 * 4) * 2) ^ ((r & 7) << 4);     // T2 swizzle, 16B slots
        *reinterpret_cast<ushort4*>(AhiB + byte) = make_ushort4(h0, h1, h2, h3);
        *reinterpret_cast<ushort4*>(AloB + byte) = make_ushort4(l0, l1, l2, l3);
    }
    __syncthreads();

    // ---- gate GEMMs: wave wv owns cols [wv*64, wv*64+64) of BOTH Z and Ht ----
    f32x4 accZ[4][4], accH[4][4];
    #pragma unroll
    for (int m = 0; m < 4; ++m)
        #pragma unroll
        for (int nf = 0; nf < 4; ++nf) {
            accZ[m][nf] = (f32x4){0.f, 0.f, 0.f, 0.f};
            accH[m][nf] = (f32x4){0.f, 0.f, 0.f, 0.f};
        }

    for (int kb = 0; kb < 8; ++kb) {
        bf16x8 ah[4], al[4];
        int koff = kb * 32 + lk * 8;
        #pragma unroll
        for (int m = 0; m < 4; ++m) {
            int row = m * 16 + l16;
            int byte = ((row * CIN + koff) * 2) ^ ((row & 7) << 4);
            ah[m] = *reinterpret_cast<const bf16x8*>(AhiB + byte);
            al[m] = *reinterpret_cast<const bf16x8*>(AloB + byte);
        }
        #pragma unroll
        for (int nf = 0; nf < 4; ++nf) {
            int nfg = wv * 4 + nf;
            bf16x8 bZh = ldfrag(wf, (nfg)      * 8 + kb, lane);
            bf16x8 bZl = ldfrag(wf, (16 + nfg) * 8 + kb, lane);
            bf16x8 bHh = ldfrag(wf, (32 + nfg) * 8 + kb, lane);
            bf16x8 bHl = ldfrag(wf, (48 + nfg) * 8 + kb, lane);
            #pragma unroll
            for (int m = 0; m < 4; ++m) {
                accZ[m][nf] = mfma16(ah[m], bZh, accZ[m][nf]);
                accZ[m][nf] = mfma16(al[m], bZh, accZ[m][nf]);
                accZ[m][nf] = mfma16(ah[m], bZl, accZ[m][nf]);
                accH[m][nf] = mfma16(ah[m], bHh, accH[m][nf]);
                accH[m][nf] = mfma16(al[m], bHh, accH[m][nf]);
                accH[m][nf] = mfma16(ah[m], bHl, accH[m][nf]);
            }
        }
    }
    __syncthreads();   // all waves done reading x tiles before h overwrites smem

    // ---- nonlinearities + GRU blend; h -> LDS as f32 (word-granular stores) ----
    #pragma unroll
    for (int nf = 0; nf < 4; ++nf) {
        int col = wv * 64 + nf * 16 + l16;
        float bzv = bz[col], bhv = bh[col];
        #pragma unroll
        for (int m = 0; m < 4; ++m) {
            #pragma unroll
            for (int i = 0; i < 4; ++i) {
                float z  = 1.f / (1.f + __expf(-(accZ[m][nf][i] + bzv)));
                float t  = __expf(2.f * (accH[m][nf][i] + bhv));
                float th = (t - 1.f) / (t + 1.f);
                float H  = (1.f - z) * th;
                float h  = (H > 0.f) ? H : (__expf(H) - 1.f);   // elu(alpha=1)
                int row = m * 16 + lk * 4 + i;                  // C/D: row=(lane>>4)*4+reg
                int byte = (row * 1024 + col * 4) ^ ((row & 7) << 4);  // f32 row stride 1 KB
                *reinterpret_cast<float*>(smem + byte) = h;
            }
        }
    }
    __syncthreads();

    // ---- out GEMM: wave wv owns rows [wv*16, wv*16+16), all 64 out cols ----
    f32x4 accO[4];
    #pragma unroll
    for (int nf = 0; nf < 4; ++nf) accO[nf] = (f32x4){0.f, 0.f, 0.f, 0.f};

    for (int kb = 0; kb < 8; ++kb) {
        int row = wv * 16 + l16;
        int e0  = kb * 32 + lk * 8;
        int b0  = (row * 1024 + e0 * 4)       ^ ((row & 7) << 4);
        int b1  = (row * 1024 + (e0 + 4) * 4) ^ ((row & 7) << 4);
        f32x4 v0 = *reinterpret_cast<const f32x4*>(smem + b0);
        f32x4 v1 = *reinterpret_cast<const f32x4*>(smem + b1);
        bf16x8 ah, al;
        #pragma unroll
        for (int j = 0; j < 8; ++j) {
            float v = (j < 4) ? v0[j] : v1[j - 4];
            unsigned short hb = f2bf(v);
            ah[j] = (short)hb;
            al[j] = (short)f2bf(v - bf2f(hb));
        }
        #pragma unroll
        for (int nf = 0; nf < 4; ++nf) {
            bf16x8 bh_ = ldfrag(wf, 512 + (nf)     * 8 + kb, lane);
            bf16x8 bl_ = ldfrag(wf, 512 + (4 + nf) * 8 + kb, lane);
            accO[nf] = mfma16(ah, bh_, accO[nf]);
            accO[nf] = mfma16(al, bh_, accO[nf]);
            accO[nf] = mfma16(ah, bl_, accO[nf]);
        }
    }
    #pragma unroll
    for (int nf = 0; nf < 4; ++nf) {
        int col = nf * 16 + l16;
        float bo = blin[col];
        #pragma unroll
        for (int i = 0; i < 4; ++i) {
            int row = row0 + wv * 16 + lk * 4 + i;
            if (row < N_ROWS) out[(size_t)row * COUT + col] = accO[nf][i] + bo;
        }
    }
}

// ---------------- fallback: round-2 f32 kernel (proven; used only if ws too small) ----------------
__global__ __launch_bounds__(256) void fallback_f32(
    const float* __restrict__ x, const float* __restrict__ mask,
    const float* __restrict__ wzr, const float* __restrict__ whr,
    const float* __restrict__ bz, const float* __restrict__ bh,
    const float* __restrict__ wlinr, const float* __restrict__ blin,
    float* __restrict__ out)
{
    __shared__ float xm[32][CIN];
    const int tid = threadIdx.x;
    const int row0 = blockIdx.x * 32;
    #pragma unroll
    for (int it = 0; it < 8; ++it) {
        int idx = it * 256 + tid;
        int r = idx >> 6, c4 = idx & 63, row = row0 + r;
        float4 v = make_float4(0.f, 0.f, 0.f, 0.f);
        if (row < N_ROWS) {
            float4 a = reinterpret_cast<const float4*>(x    + (size_t)row * CIN)[c4];
            float4 m = reinterpret_cast<const float4*>(mask + (size_t)row * CIN)[c4];
            v = make_float4(a.x * m.x, a.y * m.y, a.z * m.z, a.w * m.w);
        }
        reinterpret_cast<float4*>(&xm[r][0])[c4] = v;
    }
    __syncthreads();
    const int j0 = (tid & 63) * 4, r0 = (tid >> 6) * 8;
    float accz[4][8], acch[4][8];
    #pragma unroll
    for (int c = 0; c < 4; ++c)
        #pragma unroll
        for (int r = 0; r < 8; ++r) { accz[c][r] = 0.f; acch[c][r] = 0.f; }
    for (int k = 0; k < CIN; k += 4) {
        float4 wz4[4], wh4[4];
        #pragma unroll
        for (int kk = 0; kk < 4; ++kk) {
            float4 a0 = *reinterpret_cast<const float4*>(&wzr[(k + kk) * 256 + j0]);
            float4 a1 = *reinterpret_cast<const float4*>(&wzr[131072 + (k + kk) * 256 + j0]);
            wz4[kk] = make_float4(a0.x + a1.x, a0.y + a1.y, a0.z + a1.z, a0.w + a1.w);
            float4 b0 = *reinterpret_cast<const float4*>(&whr[(k + kk) * 256 + j0]);
            float4 b1 = *reinterpret_cast<const float4*>(&whr[131072 + (k + kk) * 256 + j0]);
            wh4[kk] = make_float4(b0.x + b1.x, b0.y + b1.y, b0.z + b1.z, b0.w + b1.w);
        }
        #pragma unroll
        for (int r = 0; r < 8; ++r) {
            float4 xv = *reinterpret_cast<const float4*>(&xm[r0 + r][k]);
            float xk[4] = {xv.x, xv.y, xv.z, xv.w};
            float wzc[4][4] = {{wz4[0].x,wz4[0].y,wz4[0].z,wz4[0].w},{wz4[1].x,wz4[1].y,wz4[1].z,wz4[1].w},
                               {wz4[2].x,wz4[2].y,wz4[2].z,wz4[2].w},{wz4[3].x,wz4[3].y,wz4[3].z,wz4[3].w}};
            float whc[4][4] = {{wh4[0].x,wh4[0].y,wh4[0].z,wh4[0].w},{wh4[1].x,wh4[1].y,wh4[1].z,wh4[1].w},
                               {wh4[2].x,wh4[2].y,wh4[2].z,wh4[2].w},{wh4[3].x,wh4[3].y,wh4[3].z,wh4[3].w}};
            #pragma unroll
            for (int kk = 0; kk < 4; ++kk)
                #pragma unroll
                for (int c = 0; c < 4; ++c) {
                    accz[c][r] = fmaf(xk[kk], wzc[kk][c], accz[c][r]);
                    acch[c][r] = fmaf(xk[kk], whc[kk][c], acch[c][r]);
                }
        }
    }
    float bzj[4], bhj[4];
    #pragma unroll
    for (int c = 0; c < 4; ++c) { bzj[c] = bz[j0 + c]; bhj[c] = bh[j0 + c]; }
    __syncthreads();
    #pragma unroll
    for (int r = 0; r < 8; ++r) {
        float hc[4];
        #pragma unroll
        for (int c = 0; c < 4; ++c) {
            float z  = 1.f / (1.f + expf(-(accz[c][r] + bzj[c])));
            float ht = tanhf(acch[c][r] + bhj[c]);
            float H  = (1.f - z) * ht;
            hc[c] = (H > 0.f) ? H : expm1f(H);
        }
        *reinterpret_cast<float4*>(&xm[r0 + r][j0]) = make_float4(hc[0], hc[1], hc[2], hc[3]);
    }
    __syncthreads();
    const int o = tid & 63;
    float acc[8];
    #pragma unroll
    for (int r = 0; r < 8; ++r) acc[r] = 0.f;
    for (int k = 0; k < CIN; k += 4) {
        float4 wv4 = *reinterpret_cast<const float4*>(&wlinr[o * 256 + k]);
        #pragma unroll
        for (int r = 0; r < 8; ++r) {
            float4 hv = *reinterpret_cast<const float4*>(&xm[r0 + r][k]);
            acc[r] = fmaf(hv.x, wv4.x, acc[r]);
            acc[r] = fmaf(hv.y, wv4.y, acc[r]);
            acc[r] = fmaf(hv.z, wv4.z, acc[r]);
            acc[r] = fmaf(hv.w, wv4.w, acc[r]);
        }
    }
    float bo = blin[o];
    #pragma unroll
    for (int r = 0; r < 8; ++r) {
        int row = row0 + r0 + r;
        if (row < N_ROWS) out[(size_t)row * COUT + o] = acc[r] + bo;
    }
}

extern "C" void kernel_launch(void* const* d_in, const int* in_sizes, int n_in,
                              void* d_out, int out_size, void* d_ws, size_t ws_size,
                              hipStream_t stream)
{
    const float* x    = (const float*)d_in[0];
    // d_in[1] edge_index, d_in[2] edge_weight: unused (K=1 identity term only)
    const float* mask = (const float*)d_in[3];
    const float* wz   = (const float*)d_in[4];
    const float* bz   = (const float*)d_in[5];
    // d_in[6] w_r, d_in[7] b_r: dead (H=0 -> reset gate unused)
    const float* wh   = (const float*)d_in[8];
    const float* bh   = (const float*)d_in[9];
    const float* wlin = (const float*)d_in[10];
    const float* blin = (const float*)d_in[11];
    float* outf = (float*)d_out;

    const size_t ws_need = 576 * 1024;   // 576 frags x 1 KB
    if (ws_size >= ws_need) {
        unsigned short* wsf = (unsigned short*)d_ws;
        prep_frags<<<144, 256, 0, stream>>>(wz, wh, wlin, wsf);
        dcrnn_mfma<<<(N_ROWS + BM - 1) / BM, 256, 0, stream>>>(
            x, mask, wsf, bz, bh, blin, outf);
    } else {
        fallback_f32<<<(N_ROWS + 31) / 32, 256, 0, stream>>>(
            x, mask, wz, wh, bz, bh, wlin, blin, outf);
    }
}

// Round 5
// 99.589 us; speedup vs baseline: 2.6841x; 1.2140x over previous
//
#include <hip/hip_runtime.h>
#include <hip/hip_bf16.h>

// DCRNN single-step, algebraically reduced (proven rounds 2-4):
//   xm = x * mask
//   Z  = sigmoid(xm @ WzE + bz),  WzE = w_z[0,0][:256] + w_z[1,0][:256]
//   Ht = tanh   (xm @ WhE + bh)
//   h  = elu((1 - Z) * Ht)         // H=0 -> Z*H drops; R/w_r/b_r dead; edges dead
//   out = h @ w_lin.T + b_lin      // f32 output
//
// Split-bf16 MFMA (v = hi + lo; hi*hi + lo*hi + hi*lo, f32 acc) — round-4 math kept
// bit-for-bit. Round-5: BM 64->32 (LDS 32 KB, acc 64 regs, 1563 blocks) for
// occupancy/latency-hiding; out-GEMM weight reads deduplicated (wave <-> nf).

typedef __attribute__((ext_vector_type(8))) short bf16x8;   // 8 bf16 = 4 VGPR
typedef __attribute__((ext_vector_type(4))) float f32x4;

constexpr int N_ROWS = 50000;
constexpr int CIN  = 256;
constexpr int COUT = 64;
constexpr int BM   = 32;

__device__ inline unsigned short f2bf(float f) {          // RNE f32 -> bf16 bits
    union { float f; unsigned u; } v; v.f = f;
    unsigned r = v.u + 0x7fffu + ((v.u >> 16) & 1u);
    return (unsigned short)(r >> 16);
}
__device__ inline float bf2f(unsigned short b) {
    union { unsigned u; float f; } v; v.u = ((unsigned)b) << 16;
    return v.f;
}
__device__ inline f32x4 mfma16(bf16x8 a, bf16x8 b, f32x4 c) {
    return __builtin_amdgcn_mfma_f32_16x16x32_bf16(a, b, c, 0, 0, 0);
}

// ---------------- weight prep: B-fragment-ordered hi/lo bf16 (proven) ----------------
// Fragment f holds, for lane l, 8 bf16: B[k = kb*32 + (l>>4)*8 + j][n = nf*16 + (l&15)]
// gate frags f = ((g*2+p)*16 + nf)*8 + kb   g:0=Z,1=H  p:0=hi,1=lo  nf<16 kb<8  -> [0,512)
// out  frags f = 512 + (p*4 + nf)*8 + kb    nf<4                               -> [512,576)
__global__ __launch_bounds__(256) void prep_frags(
    const float* __restrict__ wz, const float* __restrict__ wh,
    const float* __restrict__ wlin, unsigned short* __restrict__ ws)
{
    int t = blockIdx.x * 256 + threadIdx.x;
    int frag = t >> 6, lane = t & 63;
    if (frag >= 576) return;
    int g16 = lane & 15, kg = lane >> 4;
    unsigned short vals[8];
    if (frag < 512) {
        int kb = frag & 7, nf = (frag >> 3) & 15, p = (frag >> 7) & 1, g = frag >> 8;
        const float* wsrc = g ? wh : wz;
        int n = nf * 16 + g16;
        #pragma unroll
        for (int j = 0; j < 8; ++j) {
            int k = kb * 32 + kg * 8 + j;
            float v = wsrc[k * 256 + n] + wsrc[131072 + k * 256 + n];  // tap0 + tap1
            unsigned short hi = f2bf(v);
            vals[j] = (p == 0) ? hi : f2bf(v - bf2f(hi));
        }
    } else {
        int f = frag - 512;
        int kb = f & 7, nf = (f >> 3) & 3, p = f >> 5;
        int n = nf * 16 + g16;                       // output column o
        #pragma unroll
        for (int j = 0; j < 8; ++j) {
            int k = kb * 32 + kg * 8 + j;
            float v = wlin[n * 256 + k];             // B[k][o] = w_lin[o][k]
            unsigned short hi = f2bf(v);
            vals[j] = (p == 0) ? hi : f2bf(v - bf2f(hi));
        }
    }
    unsigned short* dst = ws + (size_t)frag * 512 + lane * 8;
    #pragma unroll
    for (int j = 0; j < 8; ++j) dst[j] = vals[j];
}

__device__ inline bf16x8 ldfrag(const unsigned short* wf, int frag, int lane) {
    return *reinterpret_cast<const bf16x8*>(wf + (size_t)frag * 512 + lane * 8);
}

// ---------------- fused MFMA kernel (BM=32) ----------------
__global__ __launch_bounds__(256, 3) void dcrnn_mfma(
    const float* __restrict__ x, const float* __restrict__ mask,
    const unsigned short* __restrict__ wf,
    const float* __restrict__ bz, const float* __restrict__ bh,
    const float* __restrict__ blin, float* __restrict__ out)
{
    __shared__ char smem[32768];               // phase A/B: Ahi|Alo bf16; phase C: h as f32
    char* AhiB = smem;                         // 16 KB, XOR-swizzled bf16 x_hi (32x256)
    char* AloB = smem + 16384;                 // 16 KB, XOR-swizzled bf16 x_lo
    const int tid = threadIdx.x, lane = tid & 63, wv = tid >> 6;
    const int l16 = lane & 15, lk = lane >> 4;
    const int row0 = blockIdx.x * BM;

    // ---- stage xm = x*mask -> hi/lo bf16 in LDS (coalesced f32x4, swizzled 8B writes) ----
    #pragma unroll
    for (int it = 0; it < 8; ++it) {
        int f = it * 256 + tid;                // float4 slot in 32x256 tile
        int r = f >> 6, c4 = f & 63;
        int row = row0 + r;
        float4 xv = make_float4(0.f, 0.f, 0.f, 0.f), mv = xv;
        if (row < N_ROWS) {
            xv = reinterpret_cast<const float4*>(x    + (size_t)row * CIN)[c4];
            mv = reinterpret_cast<const float4*>(mask + (size_t)row * CIN)[c4];
        }
        float v0 = xv.x * mv.x, v1 = xv.y * mv.y, v2 = xv.z * mv.z, v3 = xv.w * mv.w;
        unsigned short h0 = f2bf(v0), h1 = f2bf(v1), h2 = f2bf(v2), h3 = f2bf(v3);
        unsigned short l0 = f2bf(v0 - bf2f(h0)), l1 = f2bf(v1 - bf2f(h1));
        unsigned short l2 = f2bf(v2 - bf2f(h2)), l3 = f2bf(v3 - bf2f(h3));
        int byte = ((r * CIN + c4 * 4) * 2) ^ ((r & 7) << 4);     // T2 swizzle, 16B slots
        *reinterpret_cast<ushort4*>(AhiB + byte) = make_ushort4(h0, h1, h2, h3);
        *reinterpret_cast<ushort4*>(AloB + byte) = make_ushort4(l0, l1, l2, l3);
    }
    __syncthreads();

    // ---- gate GEMMs: wave wv owns cols [wv*64, wv*64+64) of BOTH Z and Ht; 32 rows ----
    f32x4 accZ[2][4], accH[2][4];
    #pragma unroll
    for (int m = 0; m < 2; ++m)
        #pragma unroll
        for (int nf = 0; nf < 4; ++nf) {
            accZ[m][nf] = (f32x4){0.f, 0.f, 0.f, 0.f};
            accH[m][nf] = (f32x4){0.f, 0.f, 0.f, 0.f};
        }

    for (int kb = 0; kb < 8; ++kb) {
        bf16x8 ah[2], al[2];
        int koff = kb * 32 + lk * 8;
        #pragma unroll
        for (int m = 0; m < 2; ++m) {
            int row = m * 16 + l16;
            int byte = ((row * CIN + koff) * 2) ^ ((row & 7) << 4);
            ah[m] = *reinterpret_cast<const bf16x8*>(AhiB + byte);
            al[m] = *reinterpret_cast<const bf16x8*>(AloB + byte);
        }
        #pragma unroll
        for (int nf = 0; nf < 4; ++nf) {
            int nfg = wv * 4 + nf;
            bf16x8 bZh = ldfrag(wf, (nfg)      * 8 + kb, lane);
            bf16x8 bZl = ldfrag(wf, (16 + nfg) * 8 + kb, lane);
            bf16x8 bHh = ldfrag(wf, (32 + nfg) * 8 + kb, lane);
            bf16x8 bHl = ldfrag(wf, (48 + nfg) * 8 + kb, lane);
            #pragma unroll
            for (int m = 0; m < 2; ++m) {
                accZ[m][nf] = mfma16(ah[m], bZh, accZ[m][nf]);
                accZ[m][nf] = mfma16(al[m], bZh, accZ[m][nf]);
                accZ[m][nf] = mfma16(ah[m], bZl, accZ[m][nf]);
                accH[m][nf] = mfma16(ah[m], bHh, accH[m][nf]);
                accH[m][nf] = mfma16(al[m], bHh, accH[m][nf]);
                accH[m][nf] = mfma16(ah[m], bHl, accH[m][nf]);
            }
        }
    }
    __syncthreads();   // all waves done reading x tiles before h overwrites smem

    // ---- nonlinearities + GRU blend; h -> LDS as f32 (word-granular stores) ----
    #pragma unroll
    for (int nf = 0; nf < 4; ++nf) {
        int col = wv * 64 + nf * 16 + l16;
        float bzv = bz[col], bhv = bh[col];
        #pragma unroll
        for (int m = 0; m < 2; ++m) {
            #pragma unroll
            for (int i = 0; i < 4; ++i) {
                float z  = 1.f / (1.f + __expf(-(accZ[m][nf][i] + bzv)));
                float t  = __expf(2.f * (accH[m][nf][i] + bhv));
                float th = (t - 1.f) / (t + 1.f);
                float H  = (1.f - z) * th;
                float h  = (H > 0.f) ? H : (__expf(H) - 1.f);   // elu(alpha=1)
                int row = m * 16 + lk * 4 + i;                  // C/D: row=(lane>>4)*4+reg
                int byte = (row * 1024 + col * 4) ^ ((row & 7) << 4);  // f32 row stride 1 KB
                *reinterpret_cast<float*>(smem + byte) = h;
            }
        }
    }
    __syncthreads();

    // ---- out GEMM: wave wv owns out-cols [wv*16, wv*16+16), all 32 rows ----
    // (deduplicated: each wave reads only its own nf's weight frags, 16 KB/wave)
    f32x4 accO[2];
    #pragma unroll
    for (int m = 0; m < 2; ++m) accO[m] = (f32x4){0.f, 0.f, 0.f, 0.f};

    for (int kb = 0; kb < 8; ++kb) {
        bf16x8 bh_ = ldfrag(wf, 512 + (wv)     * 8 + kb, lane);
        bf16x8 bl_ = ldfrag(wf, 512 + (4 + wv) * 8 + kb, lane);
        #pragma unroll
        for (int m = 0; m < 2; ++m) {
            int row = m * 16 + l16;
            int e0  = kb * 32 + lk * 8;
            int b0  = (row * 1024 + e0 * 4)      ^ ((row & 7) << 4);
            int b1  = (row * 1024 + e0 * 4 + 16) ^ ((row & 7) << 4);
            f32x4 v0 = *reinterpret_cast<const f32x4*>(smem + b0);
            f32x4 v1 = *reinterpret_cast<const f32x4*>(smem + b1);
            bf16x8 ah, al;
            #pragma unroll
            for (int j = 0; j < 8; ++j) {
                float v = (j < 4) ? v0[j] : v1[j - 4];
                unsigned short hb = f2bf(v);
                ah[j] = (short)hb;
                al[j] = (short)f2bf(v - bf2f(hb));
            }
            accO[m] = mfma16(ah, bh_, accO[m]);
            accO[m] = mfma16(al, bh_, accO[m]);
            accO[m] = mfma16(ah, bl_, accO[m]);
        }
    }
    {
        int col = wv * 16 + l16;
        float bo = blin[col];
        #pragma unroll
        for (int m = 0; m < 2; ++m)
            #pragma unroll
            for (int i = 0; i < 4; ++i) {
                int row = row0 + m * 16 + lk * 4 + i;
                if (row < N_ROWS) out[(size_t)row * COUT + col] = accO[m][i] + bo;
            }
    }
}

// ---------------- fallback: round-2 f32 kernel (proven; used only if ws too small) ----------------
__global__ __launch_bounds__(256) void fallback_f32(
    const float* __restrict__ x, const float* __restrict__ mask,
    const float* __restrict__ wzr, const float* __restrict__ whr,
    const float* __restrict__ bz, const float* __restrict__ bh,
    const float* __restrict__ wlinr, const float* __restrict__ blin,
    float* __restrict__ out)
{
    __shared__ float xm[32][CIN];
    const int tid = threadIdx.x;
    const int row0 = blockIdx.x * 32;
    #pragma unroll
    for (int it = 0; it < 8; ++it) {
        int idx = it * 256 + tid;
        int r = idx >> 6, c4 = idx & 63, row = row0 + r;
        float4 v = make_float4(0.f, 0.f, 0.f, 0.f);
        if (row < N_ROWS) {
            float4 a = reinterpret_cast<const float4*>(x    + (size_t)row * CIN)[c4];
            float4 m = reinterpret_cast<const float4*>(mask + (size_t)row * CIN)[c4];
            v = make_float4(a.x * m.x, a.y * m.y, a.z * m.z, a.w * m.w);
        }
        reinterpret_cast<float4*>(&xm[r][0])[c4] = v;
    }
    __syncthreads();
    const int j0 = (tid & 63) * 4, r0 = (tid >> 6) * 8;
    float accz[4][8], acch[4][8];
    #pragma unroll
    for (int c = 0; c < 4; ++c)
        #pragma unroll
        for (int r = 0; r < 8; ++r) { accz[c][r] = 0.f; acch[c][r] = 0.f; }
    for (int k = 0; k < CIN; k += 4) {
        float4 wz4[4], wh4[4];
        #pragma unroll
        for (int kk = 0; kk < 4; ++kk) {
            float4 a0 = *reinterpret_cast<const float4*>(&wzr[(k + kk) * 256 + j0]);
            float4 a1 = *reinterpret_cast<const float4*>(&wzr[131072 + (k + kk) * 256 + j0]);
            wz4[kk] = make_float4(a0.x + a1.x, a0.y + a1.y, a0.z + a1.z, a0.w + a1.w);
            float4 b0 = *reinterpret_cast<const float4*>(&whr[(k + kk) * 256 + j0]);
            float4 b1 = *reinterpret_cast<const float4*>(&whr[131072 + (k + kk) * 256 + j0]);
            wh4[kk] = make_float4(b0.x + b1.x, b0.y + b1.y, b0.z + b1.z, b0.w + b1.w);
        }
        #pragma unroll
        for (int r = 0; r < 8; ++r) {
            float4 xv = *reinterpret_cast<const float4*>(&xm[r0 + r][k]);
            float xk[4] = {xv.x, xv.y, xv.z, xv.w};
            float wzc[4][4] = {{wz4[0].x,wz4[0].y,wz4[0].z,wz4[0].w},{wz4[1].x,wz4[1].y,wz4[1].z,wz4[1].w},
                               {wz4[2].x,wz4[2].y,wz4[2].z,wz4[2].w},{wz4[3].x,wz4[3].y,wz4[3].z,wz4[3].w}};
            float whc[4][4] = {{wh4[0].x,wh4[0].y,wh4[0].z,wh4[0].w},{wh4[1].x,wh4[1].y,wh4[1].z,wh4[1].w},
                               {wh4[2].x,wh4[2].y,wh4[2].z,wh4[2].w},{wh4[3].x,wh4[3].y,wh4[3].z,wh4[3].w}};
            #pragma unroll
            for (int kk = 0; kk < 4; ++kk)
                #pragma unroll
                for (int c = 0; c < 4; ++c) {
                    accz[c][r] = fmaf(xk[kk], wzc[kk][c], accz[c][r]);
                    acch[c][r] = fmaf(xk[kk], whc[kk][c], acch[c][r]);
                }
        }
    }
    float bzj[4], bhj[4];
    #pragma unroll
    for (int c = 0; c < 4; ++c) { bzj[c] = bz[j0 + c]; bhj[c] = bh[j0 + c]; }
    __syncthreads();
    #pragma unroll
    for (int r = 0; r < 8; ++r) {
        float hc[4];
        #pragma unroll
        for (int c = 0; c < 4; ++c) {
            float z  = 1.f / (1.f + expf(-(accz[c][r] + bzj[c])));
            float ht = tanhf(acch[c][r] + bhj[c]);
            float H  = (1.f - z) * ht;
            hc[c] = (H > 0.f) ? H : expm1f(H);
        }
        *reinterpret_cast<float4*>(&xm[r0 + r][j0]) = make_float4(hc[0], hc[1], hc[2], hc[3]);
    }
    __syncthreads();
    const int o = tid & 63;
    float acc[8];
    #pragma unroll
    for (int r = 0; r < 8; ++r) acc[r] = 0.f;
    for (int k = 0; k < CIN; k += 4) {
        float4 wv4 = *reinterpret_cast<const float4*>(&wlinr[o * 256 + k]);
        #pragma unroll
        for (int r = 0; r < 8; ++r) {
            float4 hv = *reinterpret_cast<const float4*>(&xm[r0 + r][k]);
            acc[r] = fmaf(hv.x, wv4.x, acc[r]);
            acc[r] = fmaf(hv.y, wv4.y, acc[r]);
            acc[r] = fmaf(hv.z, wv4.z, acc[r]);
            acc[r] = fmaf(hv.w, wv4.w, acc[r]);
        }
    }
    float bo = blin[o];
    #pragma unroll
    for (int r = 0; r < 8; ++r) {
        int row = row0 + r0 + r;
        if (row < N_ROWS) out[(size_t)row * COUT + o] = acc[r] + bo;
    }
}

extern "C" void kernel_launch(void* const* d_in, const int* in_sizes, int n_in,
                              void* d_out, int out_size, void* d_ws, size_t ws_size,
                              hipStream_t stream)
{
    const float* x    = (const float*)d_in[0];
    // d_in[1] edge_index, d_in[2] edge_weight: unused (K=1 identity term only)
    const float* mask = (const float*)d_in[3];
    const float* wz   = (const float*)d_in[4];
    const float* bz   = (const float*)d_in[5];
    // d_in[6] w_r, d_in[7] b_r: dead (H=0 -> reset gate unused)
    const float* wh   = (const float*)d_in[8];
    const float* bh   = (const float*)d_in[9];
    const float* wlin = (const float*)d_in[10];
    const float* blin = (const float*)d_in[11];
    float* outf = (float*)d_out;

    const size_t ws_need = 576 * 1024;   // 576 frags x 1 KB
    if (ws_size >= ws_need) {
        unsigned short* wsf = (unsigned short*)d_ws;
        prep_frags<<<144, 256, 0, stream>>>(wz, wh, wlin, wsf);
        dcrnn_mfma<<<(N_ROWS + BM - 1) / BM, 256, 0, stream>>>(
            x, mask, wsf, bz, bh, blin, outf);
    } else {
        fallback_f32<<<(N_ROWS + 31) / 32, 256, 0, stream>>>(
            x, mask, wz, wh, bz, bh, wlin, blin, outf);
    }
}